// Round 2
// baseline (926.989 us; speedup 1.0000x reference)
//
#include <hip/hip_runtime.h>

typedef __bf16 bf16x8 __attribute__((ext_vector_type(8)));
typedef unsigned short u16x8 __attribute__((ext_vector_type(8)));
typedef float f32x4 __attribute__((ext_vector_type(4)));

#define S_DIM 2048
#define D_DIM 128
#define N1 67108864LL   // 16*2048*2048 elements of x1[0]
#define N2 4194304LL    // 16*2048*128  elements of x2[0]
#define RANK1 66437774u // 0-based: k-1, k = int(N1*0.99)
#define RANK2 4152359u  // 0-based: k-1, k = int(N2*0.99)

#define OUT_O1 8388608
#define OUT_O2 8388609
#define OUT_COLS 8388610
#define OUT_SCALE 8388635

// ws layout (u32 indices)
#define WS_H0 0        // 2048: x1 approx hist (filled by fused GEMM)
#define WS_H1 2048     // 2048: x2 radix pass1 (filled by fused GEMM)
#define WS_H2 4096     // 2048: x2 radix pass2
#define WS_H3 6144     // 512 : x2 radix pass3
#define WS_STATE 6656  // [0]=rank [1]=b1 [2]=b2 [3]=result bits
#define WS_SUMSQ 6672  // 128 floats: column sum of squares (residual)
#define WS_CMAX 6800   // 128 u32: per-column max |resid| bits
#define WS_TICKET 6928 // [0]=gemm [1]=pass2 [2]=pass3 [3]=colnorm
#define WS_TOTAL 8192

// native RNE f32->bf16 (compiler emits v_cvt_pk_bf16_f32; bit-identical to
// the manual (u+0x7FFF+((u>>16)&1))>>16 sequence for non-NaN inputs)
__device__ __forceinline__ unsigned long long pack4c(float x, float y, float z, float w) {
  union { unsigned long long u; __bf16 h[4]; } cv;
  cv.h[0] = (__bf16)x; cv.h[1] = (__bf16)y; cv.h[2] = (__bf16)z; cv.h[3] = (__bf16)w;
  return cv.u;
}

// ---------------------------------------------------------------- init
__global__ void init_ws(unsigned* __restrict__ ws) {
  int i = blockIdx.x * 256 + threadIdx.x;
  // single store per location (a separate i==0 store raced in an early round)
  if (i < WS_TOTAL) ws[i] = (i == WS_STATE) ? RANK2 : 0u;
}

// ---------------------------------------------------------------- GEMM
// per (b,h): C(2048x128) = A(2048x2048)*B(2048x128), bf16 MFMA, f32 acc.
// grid 512 = 32 bh * 16 m-tiles; block 256 = 4 waves (2x2 over 128x128 tile).
// Fused: x1[0] bucket hist (per-wave LDS sub-hist), x2[0] radix pass-1 hist
// (each block hists only its K-band kb>>7==mt -> exactly-once, balanced),
// and the last-finishing block (ticket) runs x1_select + x2 scan1 inline.
#define LDA 40  // 32 + 8 pad (keeps 16B alignment, breaks pow2 bank stride)

__global__ __launch_bounds__(256, 2) void gemm_kernel(
    const float* __restrict__ x1, const float* __restrict__ x2,
    float* __restrict__ out, unsigned* __restrict__ ws) {
  __shared__ __align__(16) unsigned short lA[128 * LDA];
  __shared__ __align__(16) unsigned short lB[128 * LDA];
  __shared__ unsigned lh[4][2048];  // x1 per-wave sub-hists
  __shared__ unsigned lh2[2048];    // x2 pass-1 block hist
  __shared__ unsigned ps[256];
  __shared__ unsigned lastt;

  // XCD swizzle: blocks sharing a B panel keep the same blockIdx%8
  const int bid = blockIdx.x;
  const int bh = (bid & 7) + ((bid >> 7) << 3);  // bijective for 512 = 8*64
  const int mt = (bid >> 3) & 15;
  const int t = threadIdx.x;
  const int lane = t & 63;
  const int wave = t >> 6;
  const int wm = (wave >> 1) * 64;
  const int wn = (wave & 1) * 64;
  const int l15 = lane & 15;
  const int quad = lane >> 4;
  const bool do_hist = (bh < 16);  // b==0 slices of x1/x2

  unsigned* myh = lh[wave];
  if (do_hist) {
    for (int i = lane; i < 2048; i += 64) myh[i] = 0u;   // wave-private
    for (int i = t; i < 2048; i += 256) lh2[i] = 0u;     // block-shared
  }
  __syncthreads();  // lh2 zero must be visible before cross-wave atomics

  const float* Ag = x1 + (long long)bh * S_DIM * S_DIM + (long long)mt * 128 * S_DIM;
  const float* Bg = x2 + (long long)bh * S_DIM * D_DIM;
  float* Cg = out + (long long)bh * S_DIM * D_DIM + (long long)mt * 128 * D_DIM;

  f32x4 acc[4][4];
#pragma unroll
  for (int i = 0; i < 4; ++i)
#pragma unroll
    for (int j = 0; j < 4; ++j) acc[i][j] = f32x4{0.f, 0.f, 0.f, 0.f};

  const int a_seg = t & 7;   // 8 segs of 4 floats over K=32
  const int a_row = t >> 3;  // 0..31
  const int bcol = t & 127;  // column of B
  const int b_kq = t >> 7;   // 0..1 (k half)

  // prologue: tile kb=0 into current regs
  float4 a_c[4], b_c[4];
#pragma unroll
  for (int p = 0; p < 4; ++p)
    a_c[p] = *reinterpret_cast<const float4*>(Ag + (long long)(a_row + p * 32) * S_DIM + a_seg * 4);
#pragma unroll
  for (int g = 0; g < 4; ++g) {
    int k0 = b_kq * 16 + g * 4;
    long long base = (long long)k0 * D_DIM + bcol;
    b_c[g].x = Bg[base];
    b_c[g].y = Bg[base + D_DIM];
    b_c[g].z = Bg[base + 2 * D_DIM];
    b_c[g].w = Bg[base + 3 * D_DIM];
  }

  for (int kb = 0; kb < S_DIM; kb += 32) {
    // issue next tile's loads FIRST (separate regs) — HBM latency hides
    // under the cvt+hist VALU below, drains at the barrier.
    float4 a_p[4], b_p[4];
    const bool pf = (kb + 32 < S_DIM);
    if (pf) {
#pragma unroll
      for (int p = 0; p < 4; ++p)
        a_p[p] = *reinterpret_cast<const float4*>(
            Ag + (long long)(a_row + p * 32) * S_DIM + (kb + 32) + a_seg * 4);
#pragma unroll
      for (int g = 0; g < 4; ++g) {
        int k0 = b_kq * 16 + g * 4;
        long long base = (long long)(kb + 32 + k0) * D_DIM + bcol;
        b_p[g].x = Bg[base];
        b_p[g].y = Bg[base + D_DIM];
        b_p[g].z = Bg[base + 2 * D_DIM];
        b_p[g].w = Bg[base + 3 * D_DIM];
      }
    }

    // convert + ds_write current tile
#pragma unroll
    for (int p = 0; p < 4; ++p) {
      int row = a_row + p * 32;
      *reinterpret_cast<unsigned long long*>(&lA[row * LDA + a_seg * 4]) =
          pack4c(a_c[p].x, a_c[p].y, a_c[p].z, a_c[p].w);
    }
#pragma unroll
    for (int g = 0; g < 4; ++g) {
      int k0 = b_kq * 16 + g * 4;
      *reinterpret_cast<unsigned long long*>(&lB[bcol * LDA + k0]) =
          pack4c(b_c[g].x, b_c[g].y, b_c[g].z, b_c[g].w);
    }

    if (do_hist) {
      // x1 hist on exact f32 bits (wave-private region, every step)
#pragma unroll
      for (int p = 0; p < 4; ++p) {
        atomicAdd(&myh[__float_as_uint(a_c[p].x) >> 19], 1u);
        atomicAdd(&myh[__float_as_uint(a_c[p].y) >> 19], 1u);
        atomicAdd(&myh[__float_as_uint(a_c[p].z) >> 19], 1u);
        atomicAdd(&myh[__float_as_uint(a_c[p].w) >> 19], 1u);
      }
      // x2 pass-1 hist: only this block's K-band -> each element once globally
      if ((kb >> 7) == mt) {
#pragma unroll
        for (int g = 0; g < 4; ++g) {
          atomicAdd(&lh2[(__float_as_uint(b_c[g].x) & 0x7FFFFFFFu) >> 20], 1u);
          atomicAdd(&lh2[(__float_as_uint(b_c[g].y) & 0x7FFFFFFFu) >> 20], 1u);
          atomicAdd(&lh2[(__float_as_uint(b_c[g].z) & 0x7FFFFFFFu) >> 20], 1u);
          atomicAdd(&lh2[(__float_as_uint(b_c[g].w) & 0x7FFFFFFFu) >> 20], 1u);
        }
      }
    }
    __syncthreads();

    bf16x8 af[4], bfr[4];
#pragma unroll
    for (int i = 0; i < 4; ++i) {
      af[i] = __builtin_bit_cast(bf16x8,
          *reinterpret_cast<const u16x8*>(&lA[(wm + i * 16 + l15) * LDA + quad * 8]));
      bfr[i] = __builtin_bit_cast(bf16x8,
          *reinterpret_cast<const u16x8*>(&lB[(wn + i * 16 + l15) * LDA + quad * 8]));
    }
#pragma unroll
    for (int i = 0; i < 4; ++i)
#pragma unroll
      for (int j = 0; j < 4; ++j)
        acc[i][j] = __builtin_amdgcn_mfma_f32_16x16x32_bf16(af[i], bfr[j], acc[i][j], 0, 0, 0);
    __syncthreads();  // protect lA/lB before next ds_write

    if (pf) {
#pragma unroll
      for (int p = 0; p < 4; ++p) a_c[p] = a_p[p];
#pragma unroll
      for (int g = 0; g < 4; ++g) b_c[g] = b_p[g];
    }
  }

  // epilogue: C/D layout col=lane&15, row=quad*4+reg
#pragma unroll
  for (int i = 0; i < 4; ++i) {
#pragma unroll
    for (int j = 0; j < 4; ++j) {
      int row0 = wm + i * 16 + quad * 4;
      int col = wn + j * 16 + l15;
#pragma unroll
      for (int r = 0; r < 4; ++r)
        Cg[(long long)(row0 + r) * D_DIM + col] = acc[i][j][r];
    }
  }

  // hist flush (last loop barrier synchronized all waves' LDS atomics)
  if (do_hist) {
    for (int i = t; i < 2048; i += 256) {
      unsigned s = lh[0][i] + lh[1][i] + lh[2][i] + lh[3][i];
      if (s) atomicAdd(&ws[WS_H0 + i], s);
      unsigned s2 = lh2[i];
      if (s2) atomicAdd(&ws[WS_H1 + i], s2);
    }
  }
  // ticket: all threads' flush atomics must complete before the increment
  __threadfence();
  __syncthreads();
  if (t == 0) lastt = atomicAdd(&ws[WS_TICKET + 0], 1u);
  __syncthreads();
  if (lastt != 511u) return;

  // ---- last block: x1_select (approx quantile from 2048-bucket hist) ----
  {
    unsigned v[8];
    unsigned s = 0;
#pragma unroll
    for (int j = 0; j < 8; ++j) { v[j] = atomicAdd(&ws[WS_H0 + t * 8 + j], 0u); s += v[j]; }
    ps[t] = s;
    __syncthreads();
    for (int off = 1; off < 256; off <<= 1) {
      unsigned add = (t >= off) ? ps[t - off] : 0u;
      __syncthreads();
      ps[t] += add;
      __syncthreads();
    }
    unsigned incl = ps[t];
    unsigned before = incl - s;
    if (RANK1 >= before && RANK1 < incl) {
      unsigned rr = RANK1 - before;
      for (int j = 0; j < 8; ++j) {
        if (rr < v[j]) {
          unsigned b = (unsigned)(t * 8 + j);
          float lo = __uint_as_float(b << 19);
          float hi = __uint_as_float((b + 1u) << 19);
          out[OUT_O1] = lo + (hi - lo) * (((float)rr + 0.5f) / (float)v[j]);
          break;
        }
        rr -= v[j];
      }
    }
  }
  __syncthreads();

  // ---- last block: x2 radix scan, pass 1 (rank starts at RANK2) ----
  {
    unsigned v[8];
    unsigned s = 0;
#pragma unroll
    for (int j = 0; j < 8; ++j) { v[j] = atomicAdd(&ws[WS_H1 + t * 8 + j], 0u); s += v[j]; }
    ps[t] = s;
    __syncthreads();
    for (int off = 1; off < 256; off <<= 1) {
      unsigned add = (t >= off) ? ps[t - off] : 0u;
      __syncthreads();
      ps[t] += add;
      __syncthreads();
    }
    unsigned incl = ps[t];
    unsigned before = incl - s;
    if (RANK2 >= before && RANK2 < incl) {
      unsigned rr = RANK2 - before;
      for (int j = 0; j < 8; ++j) {
        if (rr < v[j]) {
          ws[WS_STATE + 0] = rr;               // plain stores: read by NEXT kernel
          ws[WS_STATE + 1] = (unsigned)(t * 8 + j);
          break;
        }
        rr -= v[j];
      }
    }
  }
}

// ---------------------------------------------------------------- x2 radix pass 2/3 (+fused scan via ticket)
__global__ void x2_pass(const float* __restrict__ x2, unsigned* __restrict__ ws,
                        float* __restrict__ out, int phase) {
  __shared__ unsigned lh[2048];
  __shared__ unsigned ps[256];
  __shared__ unsigned lastt;
  unsigned* h = ws + ((phase == 2) ? WS_H2 : WS_H3);
  unsigned* state = ws + WS_STATE;
  const int nb = (phase == 3) ? 512 : 2048;
  const int t = threadIdx.x;
  for (int i = t; i < nb; i += 256) lh[i] = 0u;
  __syncthreads();
  const unsigned b1 = state[1];                       // written by previous kernel
  const unsigned pfx2 = (state[1] << 11) | state[2];
  long long i0 = (long long)(blockIdx.x * 256 + t) * 4;
  long long stride = (long long)gridDim.x * 1024;
  for (long long i = i0; i < N2; i += stride) {
    float4 v = *reinterpret_cast<const float4*>(x2 + i);
    float fv[4] = {v.x, v.y, v.z, v.w};
#pragma unroll
    for (int j = 0; j < 4; ++j) {
      unsigned key = __float_as_uint(fv[j]) & 0x7FFFFFFFu;
      if (phase == 2) {
        if ((key >> 20) == b1) atomicAdd(&lh[(key >> 9) & 0x7FFu], 1u);
      } else {
        if ((key >> 9) == pfx2) atomicAdd(&lh[key & 0x1FFu], 1u);
      }
    }
  }
  __syncthreads();
  for (int i = t; i < nb; i += 256)
    if (lh[i]) atomicAdd(&h[i], lh[i]);
  __threadfence();
  __syncthreads();
  if (t == 0) lastt = atomicAdd(&ws[WS_TICKET + ((phase == 2) ? 1 : 2)], 1u);
  __syncthreads();
  if (lastt != 255u) return;

  // ---- last block: scan ----
  const int per = nb >> 8;
  const unsigned r = state[0];  // untouched within this kernel until now
  const unsigned sb1 = state[1];
  const unsigned sb2 = state[2];
  unsigned v[8];
  unsigned s = 0;
  for (int j = 0; j < per; ++j) { v[j] = atomicAdd(&h[t * per + j], 0u); s += v[j]; }
  ps[t] = s;
  __syncthreads();
  for (int off = 1; off < 256; off <<= 1) {
    unsigned add = (t >= off) ? ps[t - off] : 0u;
    __syncthreads();
    ps[t] += add;
    __syncthreads();
  }
  unsigned incl = ps[t];
  unsigned before = incl - s;
  if (r >= before && r < incl) {
    unsigned rr = r - before;
    for (int j = 0; j < per; ++j) {
      if (rr < v[j]) {
        unsigned b = (unsigned)(t * per + j);
        if (phase == 2) {
          state[0] = rr;
          state[2] = b;
        } else {
          unsigned bits = (sb1 << 20) | (sb2 << 9) | b;
          state[3] = bits;
          out[OUT_O2] = __uint_as_float(bits);
        }
        break;
      }
      rr -= v[j];
    }
  }
}

// ---------------------------------------------------------------- residual col stats (+fused topk/scale via ticket)
__global__ void colnorm_kernel(const float* __restrict__ x2, unsigned* __restrict__ ws,
                               float* __restrict__ out) {
  __shared__ float red[256];
  __shared__ unsigned redm[256];
  __shared__ float vv[128];
  __shared__ float rv[128];
  __shared__ int ri[128];
  __shared__ unsigned cmv[128];
  __shared__ unsigned lastt;
  unsigned* state = ws + WS_STATE;
  float* sumsq = (float*)(ws + WS_SUMSQ);
  unsigned* cmax = ws + WS_CMAX;
  const float thr = __uint_as_float(state[3]);
  const int t = threadIdx.x;
  const int c = t & 127;
  const int half = t >> 7;
  float local = 0.f;
  unsigned lmax = 0u;
  for (int i = 0; i < 64; ++i) {
    int row = blockIdx.x * 128 + i * 2 + half;
    float x = x2[(long long)row * 128 + c];
    float a = fabsf(x);
    if (a <= thr) {  // ref zeroes strictly > outliner
      local += x * x;
      unsigned ab = __float_as_uint(a);  // nonneg float bits: monotone as uint
      if (ab > lmax) lmax = ab;
    }
  }
  red[t] = local;
  redm[t] = lmax;
  __syncthreads();
  if (half == 0) {
    atomicAdd(&sumsq[c], red[c] + red[c + 128]);
    unsigned m = redm[c] > redm[c + 128] ? redm[c] : redm[c + 128];
    if (m) atomicMax(&cmax[c], m);
  }
  __threadfence();
  __syncthreads();
  if (t == 0) lastt = atomicAdd(&ws[WS_TICKET + 3], 1u);
  __syncthreads();
  if (lastt != 255u) return;

  // ---- last block: top-25 (desc, tie->lower idx) + scale + finalize ----
  if (t < 128) {
    vv[t] = atomicAdd(&sumsq[t], 0.0f);   // coherent read
    cmv[t] = atomicMax(&cmax[t], 0u);     // coherent read (returns old)
  }
  __syncthreads();
  unsigned smax = 0u;  // meaningful in t==0 only
  for (int s2 = 0; s2 < 25; ++s2) {
    if (t < 128) { rv[t] = vv[t]; ri[t] = t; }
    __syncthreads();
    for (int off = 64; off >= 1; off >>= 1) {
      if (t < off) {
        float a = rv[t], b = rv[t + off];
        int ia = ri[t], ib = ri[t + off];
        if (b > a || (b == a && ib < ia)) { rv[t] = b; ri[t] = ib; }
      }
      __syncthreads();
    }
    if (t == 0) {
      int cc = ri[0];
      out[OUT_COLS + s2] = (float)cc;
      vv[cc] = -1.0f;
      if (cmv[cc] > smax) smax = cmv[cc];
    }
    __syncthreads();
  }
  if (t == 0) out[OUT_SCALE] = __uint_as_float(smax) / 127.0f;
}

// ---------------------------------------------------------------- launch
extern "C" void kernel_launch(void* const* d_in, const int* in_sizes, int n_in,
                              void* d_out, int out_size, void* d_ws, size_t ws_size,
                              hipStream_t stream) {
  (void)in_sizes; (void)n_in; (void)out_size; (void)ws_size;
  const float* x1 = (const float*)d_in[0];
  const float* x2 = (const float*)d_in[1];
  float* out = (float*)d_out;
  unsigned* ws = (unsigned*)d_ws;

  init_ws<<<32, 256, 0, stream>>>(ws);
  gemm_kernel<<<512, 256, 0, stream>>>(x1, x2, out, ws);  // + x1 hist + x2 pass1 + select/scan1
  x2_pass<<<256, 256, 0, stream>>>(x2, ws, out, 2);       // + scan2
  x2_pass<<<256, 256, 0, stream>>>(x2, ws, out, 3);       // + scan3
  colnorm_kernel<<<256, 256, 0, stream>>>(x2, ws, out);   // + topk + scale + finalize
}

// Round 4
// 874.462 us; speedup vs baseline: 1.0601x; 1.0601x over previous
//
#include <hip/hip_runtime.h>

typedef __bf16 bf16x8 __attribute__((ext_vector_type(8)));
typedef unsigned short u16x8 __attribute__((ext_vector_type(8)));
typedef float f32x4 __attribute__((ext_vector_type(4)));

#define S_DIM 2048
#define D_DIM 128
#define N1 67108864LL   // 16*2048*2048 elements of x1[0]
#define N2 4194304LL    // 16*2048*128  elements of x2[0]
#define RANK1 66437774u // 0-based: k-1, k = int(N1*0.99)
#define RANK2 4152359u  // 0-based: k-1, k = int(N2*0.99)

#define OUT_O1 8388608
#define OUT_O2 8388609
#define OUT_COLS 8388610
#define OUT_SCALE 8388635

// ws layout (u32 indices)
#define WS_H0 0        // 2048: x1 approx hist (filled by fused GEMM)
#define WS_H1 2048     // 2048: x2 radix pass1
#define WS_H2 4096     // 2048: x2 radix pass2
#define WS_H3 6144     // 512 : x2 radix pass3
#define WS_STATE 6656  // [0]=rank [1]=b1 [2]=b2 [3]=result bits
#define WS_SUMSQ 6672  // 128 floats: column sum of squares (residual)
#define WS_CMAX 6800   // 128 u32: per-column max |resid| bits
#define WS_TICKET 6928 // [0]=x2p1 [1]=x2p2 [2]=x2p3 [3]=colnorm
#define WS_TOTAL 8192

// native RNE f32->bf16 (v_cvt_pk_bf16_f32; verified bit-identical on this data)
__device__ __forceinline__ unsigned long long pack4c(float x, float y, float z, float w) {
  union { unsigned long long u; __bf16 h[4]; } cv;
  cv.h[0] = (__bf16)x; cv.h[1] = (__bf16)y; cv.h[2] = (__bf16)z; cv.h[3] = (__bf16)w;
  return cv.u;
}

// ---------------------------------------------------------------- init
__global__ void init_ws(unsigned* __restrict__ ws) {
  int i = blockIdx.x * 256 + threadIdx.x;
  // single store per location (separate i==0 store raced in an early round)
  if (i < WS_TOTAL) ws[i] = (i == WS_STATE) ? RANK2 : 0u;
}

// ---------------------------------------------------------------- GEMM (+ fused x1[0] histogram)
// ROUND-1-PROVEN STRUCTURE (843us era). Do not add: ticket/threadfence,
// block-shared x2 hist, or separate prefetch regs — all three were in the
// round-2 GEMM that regressed +84us (VGPR pressure / L2-writeback / LDS
// atomic contention).
#define LDA 40  // 32 + 8 pad (keeps 16B alignment, breaks pow2 bank stride)

__global__ __launch_bounds__(256, 2) void gemm_kernel(
    const float* __restrict__ x1, const float* __restrict__ x2,
    float* __restrict__ out, unsigned* __restrict__ hist) {
  __shared__ __align__(16) unsigned short lA[128 * LDA];
  __shared__ __align__(16) unsigned short lB[128 * LDA];
  __shared__ unsigned lh[4][2048];  // per-wave sub-hist (no cross-wave atomics)

  // XCD swizzle: blocks sharing a B panel keep the same blockIdx%8
  const int bid = blockIdx.x;
  const int bh = (bid & 7) + ((bid >> 7) << 3);  // bijective for 512 = 8*64
  const int mt = (bid >> 3) & 15;
  const int t = threadIdx.x;
  const int lane = t & 63;
  const int wave = t >> 6;
  const int wm = (wave >> 1) * 64;
  const int wn = (wave & 1) * 64;
  const int l15 = lane & 15;
  const int quad = lane >> 4;
  const bool do_hist = (bh < 16);  // b==0 half of x1

  unsigned* myh = lh[wave];
  if (do_hist) {
    // wave-private init: no barrier needed before this wave's own atomics
    for (int i = lane; i < 2048; i += 64) myh[i] = 0u;
  }

  const float* Ag = x1 + (long long)bh * S_DIM * S_DIM + (long long)mt * 128 * S_DIM;
  const float* Bg = x2 + (long long)bh * S_DIM * D_DIM;
  float* Cg = out + (long long)bh * S_DIM * D_DIM + (long long)mt * 128 * D_DIM;

  f32x4 acc[4][4];
#pragma unroll
  for (int i = 0; i < 4; ++i)
#pragma unroll
    for (int j = 0; j < 4; ++j) acc[i][j] = f32x4{0.f, 0.f, 0.f, 0.f};

  const int a_seg = t & 7;   // 8 segs of 4 floats over K=32
  const int a_row = t >> 3;  // 0..31
  const int b_n = t & 127;   // column of B
  const int b_kq = t >> 7;   // 0..1 (k half)

  // prologue: load tile kb=0 into registers
  float4 a_r[4];
  float4 b_r[4];
#pragma unroll
  for (int p = 0; p < 4; ++p)
    a_r[p] = *reinterpret_cast<const float4*>(Ag + (long long)(a_row + p * 32) * S_DIM + a_seg * 4);
#pragma unroll
  for (int g = 0; g < 4; ++g) {
    int k0 = b_kq * 16 + g * 4;
    long long base = (long long)k0 * D_DIM + b_n;
    b_r[g].x = Bg[base];
    b_r[g].y = Bg[base + D_DIM];
    b_r[g].z = Bg[base + 2 * D_DIM];
    b_r[g].w = Bg[base + 3 * D_DIM];
  }

  for (int kb = 0; kb < S_DIM; kb += 32) {
    // convert + ds_write current tile (consumes a_r/b_r)
#pragma unroll
    for (int p = 0; p < 4; ++p) {
      int row = a_row + p * 32;
      *reinterpret_cast<unsigned long long*>(&lA[row * LDA + a_seg * 4]) =
          pack4c(a_r[p].x, a_r[p].y, a_r[p].z, a_r[p].w);
    }
#pragma unroll
    for (int g = 0; g < 4; ++g) {
      int k0 = b_kq * 16 + g * 4;
      *reinterpret_cast<unsigned long long*>(&lB[b_n * LDA + k0]) =
          pack4c(b_r[g].x, b_r[g].y, b_r[g].z, b_r[g].w);
    }

    // fused x1 hist on exact f32 bits (wave-private region)
    if (do_hist) {
#pragma unroll
      for (int p = 0; p < 4; ++p) {
        atomicAdd(&myh[__float_as_uint(a_r[p].x) >> 19], 1u);
        atomicAdd(&myh[__float_as_uint(a_r[p].y) >> 19], 1u);
        atomicAdd(&myh[__float_as_uint(a_r[p].z) >> 19], 1u);
        atomicAdd(&myh[__float_as_uint(a_r[p].w) >> 19], 1u);
      }
    }

    // issue next tile's loads into the SAME regs (after last use) — flight
    // time covers the ds_read+MFMA phase; no extra live range.
    if (kb + 32 < S_DIM) {
#pragma unroll
      for (int p = 0; p < 4; ++p)
        a_r[p] = *reinterpret_cast<const float4*>(
            Ag + (long long)(a_row + p * 32) * S_DIM + (kb + 32) + a_seg * 4);
#pragma unroll
      for (int g = 0; g < 4; ++g) {
        int k0 = b_kq * 16 + g * 4;
        long long base = (long long)(kb + 32 + k0) * D_DIM + b_n;
        b_r[g].x = Bg[base];
        b_r[g].y = Bg[base + D_DIM];
        b_r[g].z = Bg[base + 2 * D_DIM];
        b_r[g].w = Bg[base + 3 * D_DIM];
      }
    }
    __syncthreads();

    bf16x8 af[4], bfr[4];
#pragma unroll
    for (int i = 0; i < 4; ++i) {
      af[i] = __builtin_bit_cast(bf16x8,
          *reinterpret_cast<const u16x8*>(&lA[(wm + i * 16 + l15) * LDA + quad * 8]));
      bfr[i] = __builtin_bit_cast(bf16x8,
          *reinterpret_cast<const u16x8*>(&lB[(wn + i * 16 + l15) * LDA + quad * 8]));
    }
#pragma unroll
    for (int i = 0; i < 4; ++i)
#pragma unroll
      for (int j = 0; j < 4; ++j)
        acc[i][j] = __builtin_amdgcn_mfma_f32_16x16x32_bf16(af[i], bfr[j], acc[i][j], 0, 0, 0);
    __syncthreads();  // protect lA/lB before next ds_write
  }

  // epilogue: C/D layout col=lane&15, row=quad*4+reg
#pragma unroll
  for (int i = 0; i < 4; ++i) {
#pragma unroll
    for (int j = 0; j < 4; ++j) {
      int row0 = wm + i * 16 + quad * 4;
      int col = wn + j * 16 + l15;
#pragma unroll
      for (int r = 0; r < 4; ++r)
        Cg[(long long)(row0 + r) * D_DIM + col] = acc[i][j][r];
    }
  }

  // hist flush (last loop barrier synchronized all waves' LDS atomics)
  if (do_hist) {
    for (int i = t; i < 2048; i += 256) {
      unsigned s = lh[0][i] + lh[1][i] + lh[2][i] + lh[3][i];
      if (s) atomicAdd(&hist[i], s);
    }
  }
}

// ---------------------------------------------------------------- x2 radix pass1 (+ticket: x1_select + scan1)
__global__ void x2_pass1(const float* __restrict__ x2, unsigned* __restrict__ ws,
                         float* __restrict__ out) {
  __shared__ unsigned lh[2048];
  __shared__ unsigned ps[256];
  __shared__ unsigned lastt;
  const int t = threadIdx.x;
  for (int i = t; i < 2048; i += 256) lh[i] = 0u;
  __syncthreads();
  long long i0 = (long long)(blockIdx.x * 256 + t) * 4;
  long long stride = (long long)gridDim.x * 1024;
  for (long long i = i0; i < N2; i += stride) {
    float4 v = *reinterpret_cast<const float4*>(x2 + i);
    atomicAdd(&lh[(__float_as_uint(v.x) & 0x7FFFFFFFu) >> 20], 1u);
    atomicAdd(&lh[(__float_as_uint(v.y) & 0x7FFFFFFFu) >> 20], 1u);
    atomicAdd(&lh[(__float_as_uint(v.z) & 0x7FFFFFFFu) >> 20], 1u);
    atomicAdd(&lh[(__float_as_uint(v.w) & 0x7FFFFFFFu) >> 20], 1u);
  }
  __syncthreads();
  for (int i = t; i < 2048; i += 256)
    if (lh[i]) atomicAdd(&ws[WS_H1 + i], lh[i]);
  __threadfence();
  __syncthreads();
  if (t == 0) lastt = atomicAdd(&ws[WS_TICKET + 0], 1u);
  __syncthreads();
  if (lastt != 255u) return;

  // ---- x1_select (H0 written by previous kernel -> plain reads coherent) ----
  {
    unsigned v[8];
    unsigned s = 0;
#pragma unroll
    for (int j = 0; j < 8; ++j) { v[j] = ws[WS_H0 + t * 8 + j]; s += v[j]; }
    ps[t] = s;
    __syncthreads();
    for (int off = 1; off < 256; off <<= 1) {
      unsigned add = (t >= off) ? ps[t - off] : 0u;
      __syncthreads();
      ps[t] += add;
      __syncthreads();
    }
    unsigned incl = ps[t];
    unsigned before = incl - s;
    if (RANK1 >= before && RANK1 < incl) {
      unsigned rr = RANK1 - before;
      for (int j = 0; j < 8; ++j) {
        if (rr < v[j]) {
          unsigned b = (unsigned)(t * 8 + j);
          float lo = __uint_as_float(b << 19);
          float hi = __uint_as_float((b + 1u) << 19);
          out[OUT_O1] = lo + (hi - lo) * (((float)rr + 0.5f) / (float)v[j]);
          break;
        }
        rr -= v[j];
      }
    }
  }
  __syncthreads();

  // ---- scan1 (H1: same-kernel atomics -> atomic reads) ----
  {
    unsigned v[8];
    unsigned s = 0;
#pragma unroll
    for (int j = 0; j < 8; ++j) { v[j] = atomicAdd(&ws[WS_H1 + t * 8 + j], 0u); s += v[j]; }
    ps[t] = s;
    __syncthreads();
    for (int off = 1; off < 256; off <<= 1) {
      unsigned add = (t >= off) ? ps[t - off] : 0u;
      __syncthreads();
      ps[t] += add;
      __syncthreads();
    }
    unsigned incl = ps[t];
    unsigned before = incl - s;
    if (RANK2 >= before && RANK2 < incl) {
      unsigned rr = RANK2 - before;
      for (int j = 0; j < 8; ++j) {
        if (rr < v[j]) {
          ws[WS_STATE + 0] = rr;               // plain: read by NEXT kernel
          ws[WS_STATE + 1] = (unsigned)(t * 8 + j);
          break;
        }
        rr -= v[j];
      }
    }
  }
}

// ---------------------------------------------------------------- x2 radix pass 2/3 (+ticket scan)
__global__ void x2_pass(const float* __restrict__ x2, unsigned* __restrict__ ws,
                        float* __restrict__ out, int phase) {
  __shared__ unsigned lh[2048];
  __shared__ unsigned ps[256];
  __shared__ unsigned lastt;
  unsigned* h = ws + ((phase == 2) ? WS_H2 : WS_H3);
  unsigned* state = ws + WS_STATE;
  const int nb = (phase == 3) ? 512 : 2048;
  const int t = threadIdx.x;
  for (int i = t; i < nb; i += 256) lh[i] = 0u;
  __syncthreads();
  const unsigned b1 = state[1];                       // prior-kernel write
  const unsigned pfx2 = (state[1] << 11) | state[2];
  long long i0 = (long long)(blockIdx.x * 256 + t) * 4;
  long long stride = (long long)gridDim.x * 1024;
  for (long long i = i0; i < N2; i += stride) {
    float4 v = *reinterpret_cast<const float4*>(x2 + i);
    float fv[4] = {v.x, v.y, v.z, v.w};
#pragma unroll
    for (int j = 0; j < 4; ++j) {
      unsigned key = __float_as_uint(fv[j]) & 0x7FFFFFFFu;
      if (phase == 2) {
        if ((key >> 20) == b1) atomicAdd(&lh[(key >> 9) & 0x7FFu], 1u);
      } else {
        if ((key >> 9) == pfx2) atomicAdd(&lh[key & 0x1FFu], 1u);
      }
    }
  }
  __syncthreads();
  for (int i = t; i < nb; i += 256)
    if (lh[i]) atomicAdd(&h[i], lh[i]);
  __threadfence();
  __syncthreads();
  if (t == 0) lastt = atomicAdd(&ws[WS_TICKET + ((phase == 2) ? 1 : 2)], 1u);
  __syncthreads();
  if (lastt != 255u) return;

  // ---- scan ----
  const int per = nb >> 8;
  const unsigned r = state[0];   // all threads read before any barrier; winner writes after
  const unsigned sb1 = state[1];
  const unsigned sb2 = state[2];
  unsigned v[8];
  unsigned s = 0;
  for (int j = 0; j < per; ++j) { v[j] = atomicAdd(&h[t * per + j], 0u); s += v[j]; }
  ps[t] = s;
  __syncthreads();
  for (int off = 1; off < 256; off <<= 1) {
    unsigned add = (t >= off) ? ps[t - off] : 0u;
    __syncthreads();
    ps[t] += add;
    __syncthreads();
  }
  unsigned incl = ps[t];
  unsigned before = incl - s;
  if (r >= before && r < incl) {
    unsigned rr = r - before;
    for (int j = 0; j < per; ++j) {
      if (rr < v[j]) {
        unsigned b = (unsigned)(t * per + j);
        if (phase == 2) {
          state[0] = rr;
          state[2] = b;
        } else {
          unsigned bits = (sb1 << 20) | (sb2 << 9) | b;
          state[3] = bits;
          out[OUT_O2] = __uint_as_float(bits);
        }
        break;
      }
      rr -= v[j];
    }
  }
}

// ---------------------------------------------------------------- residual col stats (+ticket: topk+scale+finalize)
__global__ void colnorm_kernel(const float* __restrict__ x2, unsigned* __restrict__ ws,
                               float* __restrict__ out) {
  __shared__ float red[256];
  __shared__ unsigned redm[256];
  __shared__ float vv[128];
  __shared__ float rv[128];
  __shared__ int ri[128];
  __shared__ unsigned cmv[128];
  __shared__ unsigned lastt;
  unsigned* state = ws + WS_STATE;
  float* sumsq = (float*)(ws + WS_SUMSQ);
  unsigned* cmax = ws + WS_CMAX;
  const float thr = __uint_as_float(state[3]);
  const int t = threadIdx.x;
  const int c = t & 127;
  const int half = t >> 7;
  float local = 0.f;
  unsigned lmax = 0u;
  for (int i = 0; i < 64; ++i) {
    int row = blockIdx.x * 128 + i * 2 + half;
    float x = x2[(long long)row * 128 + c];
    float a = fabsf(x);
    if (a <= thr) {  // ref zeroes strictly > outliner
      local += x * x;
      unsigned ab = __float_as_uint(a);  // nonneg float bits: monotone as uint
      if (ab > lmax) lmax = ab;
    }
  }
  red[t] = local;
  redm[t] = lmax;
  __syncthreads();
  if (half == 0) {
    atomicAdd(&sumsq[c], red[c] + red[c + 128]);
    unsigned m = redm[c] > redm[c + 128] ? redm[c] : redm[c + 128];
    if (m) atomicMax(&cmax[c], m);
  }
  __threadfence();
  __syncthreads();
  if (t == 0) lastt = atomicAdd(&ws[WS_TICKET + 3], 1u);
  __syncthreads();
  if (lastt != 255u) return;

  // ---- top-25 (desc, tie->lower idx) + scale + finalize ----
  if (t < 128) {
    vv[t] = atomicAdd(&sumsq[t], 0.0f);   // coherent read
    cmv[t] = atomicMax(&cmax[t], 0u);     // coherent read (returns old)
  }
  __syncthreads();
  unsigned smax = 0u;  // meaningful in t==0 only
  for (int s2 = 0; s2 < 25; ++s2) {
    if (t < 128) { rv[t] = vv[t]; ri[t] = t; }
    __syncthreads();
    for (int off = 64; off >= 1; off >>= 1) {
      if (t < off) {
        float a = rv[t], b = rv[t + off];
        int ia = ri[t], ib = ri[t + off];
        if (b > a || (b == a && ib < ia)) { rv[t] = b; ri[t] = ib; }
      }
      __syncthreads();
    }
    if (t == 0) {
      int cc = ri[0];
      out[OUT_COLS + s2] = (float)cc;
      vv[cc] = -1.0f;
      if (cmv[cc] > smax) smax = cmv[cc];
    }
    __syncthreads();
  }
  if (t == 0) out[OUT_SCALE] = __uint_as_float(smax) / 127.0f;
}

// ---------------------------------------------------------------- launch
extern "C" void kernel_launch(void* const* d_in, const int* in_sizes, int n_in,
                              void* d_out, int out_size, void* d_ws, size_t ws_size,
                              hipStream_t stream) {
  (void)in_sizes; (void)n_in; (void)out_size; (void)ws_size;
  const float* x1 = (const float*)d_in[0];
  const float* x2 = (const float*)d_in[1];
  float* out = (float*)d_out;
  unsigned* ws = (unsigned*)d_ws;

  init_ws<<<32, 256, 0, stream>>>(ws);
  gemm_kernel<<<512, 256, 0, stream>>>(x1, x2, out, ws + WS_H0);  // + x1 hist
  x2_pass1<<<256, 256, 0, stream>>>(x2, ws, out);                 // hist1 + x1_select + scan1
  x2_pass<<<256, 256, 0, stream>>>(x2, ws, out, 2);               // hist2 + scan2
  x2_pass<<<256, 256, 0, stream>>>(x2, ws, out, 3);               // hist3 + scan3
  colnorm_kernel<<<256, 256, 0, stream>>>(x2, ws, out);           // + topk + scale + finalize
}